// Round 6
// baseline (452.715 us; speedup 1.0000x reference)
//
#include <hip/hip_runtime.h>
#include <stdint.h>
#include <math.h>

// x[B,M,D] fp32, center[M,K,D] fp32
#define B_TOT 16384
#define M_TOT 16
#define K_TOT 256
#define D_TOT 64
#define CHUNKS 128
#define ROWS_PER_BLOCK 128  // B_TOT / CHUNKS

typedef unsigned long long ull;

// Order-preserving float->uint map
__device__ __forceinline__ uint32_t f32_key(float f) {
  uint32_t u = __float_as_uint(f);
  return (u & 0x80000000u) ? ~u : (u | 0x80000000u);
}
__device__ __forceinline__ float xlane(float v, int l) {
  return __uint_as_float(__builtin_amdgcn_readlane(__float_as_uint(v), l));
}
__device__ __forceinline__ ull u64min(ull a, ull b) { return a < b ? a : b; }

// *** R6: XLA-CPU (AVX512, 16-lane) vectorized row-reduce emulation ***
// reduce(mul(x,x)) fused: q_d = fl(x_d*x_d); init-0 vector accumulator,
// 4 iterations: r_j = ((q_j + q_{16+j}) + q_{32+j}) + q_{48+j};
// horizontal shuffle-halving: 16->8->4->2->1.
#define XLA_SUM64_LANE16(RES, P)                                      \
  do {                                                                \
    float _r[16];                                                     \
    _Pragma("unroll") for (int _j = 0; _j < 16; ++_j) _r[_j] = P(_j); \
    _Pragma("unroll") for (int _mm = 1; _mm < 4; ++_mm)               \
      _Pragma("unroll") for (int _j = 0; _j < 16; ++_j) {             \
        float _q = P(16 * _mm + _j);                                  \
        _r[_j] = _r[_j] + _q;                                         \
      }                                                               \
    float _u[8];                                                      \
    _Pragma("unroll") for (int _j = 0; _j < 8; ++_j) _u[_j] = _r[_j] + _r[_j + 8]; \
    float _v[4];                                                      \
    _Pragma("unroll") for (int _j = 0; _j < 4; ++_j) _v[_j] = _u[_j] + _u[_j + 4]; \
    float _w0 = _v[0] + _v[2];                                        \
    float _w1 = _v[1] + _v[3];                                        \
    RES = _w0 + _w1;                                                  \
  } while (0)

// Thread t owns cluster k=t. Waves independent in scoring; combined in Phase B.
__global__ __launch_bounds__(256, 4) void mkmeans_fwd(
    const float* __restrict__ x, const float* __restrict__ center,
    float* __restrict__ recon, float* __restrict__ outC, float* __restrict__ outL)
{
  // Bit-exact emulation (plain mul/add, fixed association):
#pragma clang fp contract(off)
#pragma clang fp reassociate(off)
  __shared__ ull s_partial[4][ROWS_PER_BLOCK];
  __shared__ float s_x[ROWS_PER_BLOCK];

  const int t = threadIdx.x;
  const int lane = t & 63;
  const int wave = t >> 6;
  const int bi = blockIdx.x;
  const int m = bi & (M_TOT - 1);
  const int chunk = bi >> 4;
  const int b0 = chunk * ROWS_PER_BLOCK;

  // ---- center row k=t into 64 VGPRs ----
  const float* crow = center + ((size_t)(m * K_TOT + t) * D_TOT);
  float c[64];
#pragma unroll
  for (int i = 0; i < 16; ++i) {
    float4 v = reinterpret_cast<const float4*>(crow)[i];
    c[4 * i + 0] = v.x; c[4 * i + 1] = v.y; c[4 * i + 2] = v.z; c[4 * i + 3] = v.w;
  }

  // ---- c_sq: same XLA lane-16 tree (bits irrelevant at ulp(0.0064)~5e-10,
  //      but faithful) ----
  float c_sq;
#define PC(I) (c[(I)] * c[(I)])
  XLA_SUM64_LANE16(c_sq, PC);
#undef PC

  // ---- Output 1: center passthrough (chunk-0 blocks) ----
  if (chunk == 0) {
    const float* src = center + (size_t)m * (K_TOT * D_TOT);
    float* dst = outC + (size_t)m * (K_TOT * D_TOT);
    for (int i = t; i < K_TOT * D_TOT; i += 256) dst[i] = src[i];
  }

  // ---- Phase 0: x_sq for the block's 128 rows, XLA lane-16 tree ----
  if (t < ROWS_PER_BLOCK) {
    const float* xr = x + ((size_t)((b0 + t) * M_TOT + m)) * D_TOT;
    float xsq;
#define PX(I) (xr[(I)] * xr[(I)])
    XLA_SUM64_LANE16(xsq, PX);
#undef PX
    s_x[t] = xsq;
  }
  __syncthreads();

  // ---- Phase A: scoring ----
  float xv = x[((size_t)(b0 * M_TOT + m)) * D_TOT + lane];

  for (int j = 0; j < ROWS_PER_BLOCK; ++j) {
    float xv_next = 0.f;
    if (j + 1 < ROWS_PER_BLOCK)
      xv_next = x[((size_t)((b0 + j + 1) * M_TOT + m)) * D_TOT + lane];

    const float x_sq = s_x[j];

    // dot: fixed mul+add chain. Per error budget, any fp32 dot chain is
    // within ~0.01 quantum of the ref's Eigen dot -> <=~0.4 expected flips.
    float acc0 = 0.f, acc1 = 0.f, acc2 = 0.f, acc3 = 0.f;
#define SSE_STEP(A, L, O)                                        \
    do {                                                         \
      float m3 = c[(O) + 12 + (L)] * xlane(xv, (O) + 12 + (L));  \
      float s3 = m3 + (A);                                       \
      float m2 = c[(O) + 8 + (L)] * xlane(xv, (O) + 8 + (L));    \
      float s2 = m2 + s3;                                        \
      float m1 = c[(O) + 4 + (L)] * xlane(xv, (O) + 4 + (L));    \
      float s1 = m1 + s2;                                        \
      float m0 = c[(O) + 0 + (L)] * xlane(xv, (O) + 0 + (L));    \
      (A) = m0 + s1;                                             \
    } while (0)
#pragma unroll
    for (int it = 0; it < 4; ++it) {
      const int o = 16 * it;
      SSE_STEP(acc0, 0, o);
      SSE_STEP(acc1, 1, o);
      SSE_STEP(acc2, 2, o);
      SSE_STEP(acc3, 3, o);
    }
#undef SSE_STEP
    const float dot = (acc0 + acc1) + (acc2 + acc3);

    // dist = (c_sq - 2.0*dot) + x_sq  [jax source order; XLA emits plain
    // fmul/fsub/fadd left-assoc, no contraction]
    const float two_dot = 2.0f * dot;  // exact
    const float dist = (c_sq - two_dot) + x_sq;
    // Correctly-rounded f32 sqrt (matches llvm.sqrt.f32 / np.sqrt).
    const float s = (float)sqrt((double)dist);

    // per-wave argmin, ties -> lowest lane (== lowest k)
    uint32_t key = f32_key(s);
    uint32_t kmin = key;
#pragma unroll
    for (int off = 1; off < 64; off <<= 1) {
      uint32_t o2 = (uint32_t)__shfl_xor((int)kmin, off, 64);
      kmin = kmin < o2 ? kmin : o2;
    }
    const ull ball = __ballot(key == kmin);
    if (lane == 0) {
      const int kw = wave * 64 + (__ffsll((long long)ball) - 1);
      s_partial[wave][j] = (((ull)kmin) << 32) | (unsigned)kw;
    }
    xv = xv_next;
  }
  __syncthreads();

  // ---- Phase B: combine wave partials, write recon + labels ----
  for (int jj = 0; jj < ROWS_PER_BLOCK / 4; ++jj) {
    const int j = wave * (ROWS_PER_BLOCK / 4) + jj;
    const int b = b0 + j;
    const ull g = u64min(u64min(s_partial[0][j], s_partial[1][j]),
                         u64min(s_partial[2][j], s_partial[3][j]));
    const int kstar = (int)(g & 0xffffffffull);
    const float cv = center[((size_t)(m * K_TOT + kstar)) * D_TOT + lane];
    recon[((size_t)(b * M_TOT + m)) * D_TOT + lane] = cv;
    if (lane == 0) outL[(size_t)b * M_TOT + m] = (float)kstar;
  }
}

extern "C" void kernel_launch(void* const* d_in, const int* in_sizes, int n_in,
                              void* d_out, int out_size, void* d_ws, size_t ws_size,
                              hipStream_t stream) {
  const float* x = (const float*)d_in[0];
  const float* center = (const float*)d_in[1];
  float* recon = (float*)d_out;                         // [B,M,D]
  float* outC = recon + (size_t)B_TOT * M_TOT * D_TOT;  // [M,K,D]
  float* outL = outC + (size_t)M_TOT * K_TOT * D_TOT;   // [B,M,1]

  mkmeans_fwd<<<dim3(CHUNKS * M_TOT), dim3(256), 0, stream>>>(x, center, recon, outC, outL);
}